// Round 5
// baseline (1073.674 us; speedup 1.0000x reference)
//
#include <hip/hip_runtime.h>
#include <hip/hip_fp16.h>

// B=1024, T=512, H=128, G=4H=512, IN=1
#define TT 512
#define RR 4    // rows per block -> 256 blocks, all CUs busy

using f16   = _Float16;
using f16x8 = __attribute__((ext_vector_type(8))) _Float16;
using f32x4 = __attribute__((ext_vector_type(4))) float;

__device__ __forceinline__ float sigm(float x) {
    return __builtin_amdgcn_rcpf(1.0f + __builtin_amdgcn_exp2f(x * -1.44269504f));
}
__device__ __forceinline__ float tanh_(float x) {
    return 1.0f - 2.0f * __builtin_amdgcn_rcpf(1.0f + __builtin_amdgcn_exp2f(x * 2.88539008f));
}

// LDS layout (dynamic, 151552 B):
//   [0,131072)        Whh2 f16 [512][128], chunk-swizzled (byte^((n&7)<<4))
//   [131072,133120)   h1 mailbox: 2 x [4 rows][256 B] f16, swizzled
//   [133120,135168)   h2 mailbox: 2 x [4 rows][256 B]
//   [135168,151552)   per-wave strips: wave w at +w*2048, 8 slots x 256 B
__global__ __launch_bounds__(512, 2) void lstm2_spec(
    const float* __restrict__ x,
    const float* __restrict__ Wih1,
    const float* __restrict__ Whh1,
    const float* __restrict__ bih1,
    const float* __restrict__ bhh1,
    const float* __restrict__ Wih2,
    const float* __restrict__ Whh2,
    const float* __restrict__ bih2,
    const float* __restrict__ bhh2,
    const float* __restrict__ Wl,
    const float* __restrict__ bl,
    float* __restrict__ out)
{
    extern __shared__ char smem[];
    char* const whh2L  = smem;
    char* const h1m    = smem + 131072;
    char* const h2m    = smem + 133120;
    char* const strips = smem + 135168;

    const int tid  = threadIdx.x;
    const int w    = tid >> 6;
    const int lane = tid & 63;
    const int r    = lane & 15;
    const int q    = lane >> 4;
    const int rowbase = blockIdx.x * RR;
    const bool isL1 = (w < 4);       // waves 0-3: layer 1; 4-7: layer 2 (lagged)
    const int  jj   = isL1 ? w : (w - 4);   // owns h-units [32jj, 32jj+32)

    // ---- zero both mailboxes (4096 B) ----
    {
        unsigned* z = (unsigned*)h1m;
        z[tid] = 0u; z[tid + 512] = 0u;
    }
    // ---- stage Whh2 -> LDS f16, swizzled ----
    for (int it = 0; it < 64; ++it) {
        int pp = tid + it * 512;
        int n  = pp >> 6;          // gate row 0..511
        int kp = pp & 63;          // k-pair
        float2 v = *(const float2*)(Whh2 + n * 128 + kp * 2);
        union { f16 h[2]; unsigned u; } cv;
        cv.h[0] = (f16)v.x; cv.h[1] = (f16)v.y;
        *(unsigned*)(whh2L + n * 256 + ((kp * 4) ^ ((n & 7) << 4))) = cv.u;
    }

    // ---- per-lane constants (unit u = 32jj + 16t2 + r, gate g) ----
    float bo[2][4], w1o[2][4];
    #pragma unroll
    for (int t2 = 0; t2 < 2; ++t2)
        #pragma unroll
        for (int g = 0; g < 4; ++g) {
            int n = g * 128 + jj * 32 + t2 * 16 + r;
            if (isL1) { bo[t2][g] = bih1[n] + bhh1[n]; w1o[t2][g] = Wih1[n]; }
            else      { bo[t2][g] = bih2[n] + bhh2[n]; w1o[t2][g] = 0.f; }
        }
    float wl0 = 0.f, wl1 = 0.f;
    if (!isL1) { wl0 = Wl[jj * 32 + r]; wl1 = Wl[jj * 32 + 16 + r]; }
    const float bl0 = bl[0];

    // ---- register B-fragments: L1 waves = Whh1, L2 waves = Wih2 (shared var) ----
    const float* const Wreg = isL1 ? Whh1 : Wih2;
    f16x8 wreg[4][2][4];
    #pragma unroll
    for (int g = 0; g < 4; ++g)
        #pragma unroll
        for (int t2 = 0; t2 < 2; ++t2) {
            int n = g * 128 + jj * 32 + t2 * 16 + r;
            #pragma unroll
            for (int kt = 0; kt < 4; ++kt) {
                const float4* p = (const float4*)(Wreg + n * 128 + kt * 32 + q * 8);
                float4 a = p[0], b = p[1];
                wreg[g][t2][kt] = f16x8{ (f16)a.x,(f16)a.y,(f16)a.z,(f16)a.w,
                                         (f16)b.x,(f16)b.y,(f16)b.z,(f16)b.w };
            }
        }

    // ---- address constants ----
    const int swz = (r & 7) << 4;
    int kxo[4];                       // swizzled within-row chunk offset
    #pragma unroll
    for (int kt = 0; kt < 4; ++kt) kxo[kt] = (kt * 64 + q * 16) ^ swz;
    int afo[4];                       // A-frag offsets in a 4-row mailbox buffer
    #pragma unroll
    for (int kt = 0; kt < 4; ++kt) afo[kt] = r * 256 + kxo[kt];
    int nbt[2];                       // Whh2 LDS row bases (g stride = 32768 B)
    #pragma unroll
    for (int t2 = 0; t2 < 2; ++t2) nbt[t2] = (jj * 32 + t2 * 16 + r) * 256;
    int hwo[2];                       // mailbox write offsets (row q, unit u)
    #pragma unroll
    for (int t2 = 0; t2 < 2; ++t2) {
        int u = jj * 32 + t2 * 16 + r;
        hwo[t2] = q * 256 + ((2 * u) ^ (q << 4));
    }
    char* const strip = strips + w * 2048;
    const bool rlow = (r < 4);
    const f16x8 zf = f16x8{0,0,0,0,0,0,0,0};

    float cst[2] = {0.f, 0.f};        // c1 (L1 waves) / c2 (L2 waves)
    float h2f[2] = {0.f, 0.f};

    __syncthreads();

    // iter i: L1 computes h1_i (i<TT); L2 computes h2_{i-1} (i>=1). One barrier.
    for (int i = 0; i <= TT; ++i) {
        f32x4 acc[4][2] = {{{0,0,0,0},{0,0,0,0}},{{0,0,0,0},{0,0,0,0}},
                           {{0,0,0,0},{0,0,0,0}},{{0,0,0,0},{0,0,0,0}}};
        if (isL1) {
            if (i < TT) {
                const char* h1r = h1m + ((i + 1) & 1) * 1024;   // h1_{i-1}
                char*       h1w = h1m + (i & 1) * 1024;         // h1_i
                const float xv = x[(rowbase + q) * TT + i];
                #pragma unroll
                for (int kt = 0; kt < 4; ++kt) {
                    f16x8 af = rlow ? *(const f16x8*)(h1r + afo[kt]) : zf;
                    #pragma unroll
                    for (int g = 0; g < 4; ++g)
                        #pragma unroll
                        for (int t2 = 0; t2 < 2; ++t2)
                            acc[g][t2] = __builtin_amdgcn_mfma_f32_16x16x32_f16(
                                af, wreg[g][t2][kt], acc[g][t2], 0, 0, 0);
                }
                if (q == 0) {
                    #pragma unroll
                    for (int g = 0; g < 4; ++g)
                        #pragma unroll
                        for (int t2 = 0; t2 < 2; ++t2)
                            *(f32x4*)(strip + (g * 2 + t2) * 256 + r * 16) = acc[g][t2];
                }
                #pragma unroll
                for (int t2 = 0; t2 < 2; ++t2) {
                    float pg[4];
                    #pragma unroll
                    for (int g = 0; g < 4; ++g)
                        pg[g] = ((const float*)(strip + (g * 2 + t2) * 256 + r * 16))[q]
                                + fmaf(xv, w1o[t2][g], bo[t2][g]);
                    float gi = sigm(pg[0]), gf = sigm(pg[1]);
                    float gg = tanh_(pg[2]), go = sigm(pg[3]);
                    cst[t2] = gf * cst[t2] + gi * gg;
                    float hv = go * tanh_(cst[t2]);
                    *(f16*)(h1w + hwo[t2]) = (f16)hv;
                }
            }
        } else {
            if (i >= 1) {
                const char* h1r = h1m + ((i + 1) & 1) * 1024;   // h1_{i-1}
                const char* h2r = h2m + (i & 1) * 1024;         // h2_{i-2}
                char*       h2w = h2m + ((i + 1) & 1) * 1024;   // h2_{i-1}
                #pragma unroll
                for (int kt = 0; kt < 4; ++kt) {
                    f16x8 af = rlow ? *(const f16x8*)(h1r + afo[kt]) : zf;
                    #pragma unroll
                    for (int g = 0; g < 4; ++g)
                        #pragma unroll
                        for (int t2 = 0; t2 < 2; ++t2)
                            acc[g][t2] = __builtin_amdgcn_mfma_f32_16x16x32_f16(
                                af, wreg[g][t2][kt], acc[g][t2], 0, 0, 0);
                }
                #pragma unroll
                for (int kt = 0; kt < 4; ++kt) {
                    f16x8 ah = rlow ? *(const f16x8*)(h2r + afo[kt]) : zf;
                    #pragma unroll
                    for (int g = 0; g < 4; ++g)
                        #pragma unroll
                        for (int t2 = 0; t2 < 2; ++t2) {
                            f16x8 bf = *(const f16x8*)(whh2L + g * 32768 + nbt[t2] + kxo[kt]);
                            acc[g][t2] = __builtin_amdgcn_mfma_f32_16x16x32_f16(
                                ah, bf, acc[g][t2], 0, 0, 0);
                        }
                }
                if (q == 0) {
                    #pragma unroll
                    for (int g = 0; g < 4; ++g)
                        #pragma unroll
                        for (int t2 = 0; t2 < 2; ++t2)
                            *(f32x4*)(strip + (g * 2 + t2) * 256 + r * 16) = acc[g][t2];
                }
                #pragma unroll
                for (int t2 = 0; t2 < 2; ++t2) {
                    float pg[4];
                    #pragma unroll
                    for (int g = 0; g < 4; ++g)
                        pg[g] = ((const float*)(strip + (g * 2 + t2) * 256 + r * 16))[q]
                                + bo[t2][g];
                    float gi = sigm(pg[0]), gf = sigm(pg[1]);
                    float gg = tanh_(pg[2]), go = sigm(pg[3]);
                    cst[t2] = gf * cst[t2] + gi * gg;
                    float hv = go * tanh_(cst[t2]);
                    h2f[t2] = hv;
                    *(f16*)(h2w + hwo[t2]) = (f16)hv;
                }
            }
        }
        __syncthreads();
    }

    // ---- out[m] = h2_511[m] @ Wl + bl ----
    if (!isL1) {
        float v = h2f[0] * wl0 + h2f[1] * wl1;
        v += __shfl_xor(v, 1);
        v += __shfl_xor(v, 2);
        v += __shfl_xor(v, 4);
        v += __shfl_xor(v, 8);           // lanes r==0: sum over wave's 32 units
        if (r == 0) ((float*)strips)[q * 4 + jj] = v;
    }
    __syncthreads();
    if (tid < RR) {
        float a = bl0;
        #pragma unroll
        for (int s = 0; s < 4; ++s) a += ((const float*)strips)[tid * 4 + s];
        out[rowbase + tid] = a;
    }
}

extern "C" void kernel_launch(void* const* d_in, const int* in_sizes, int n_in,
                              void* d_out, int out_size, void* d_ws, size_t ws_size,
                              hipStream_t stream) {
    const float* x    = (const float*)d_in[0];
    const float* Wih1 = (const float*)d_in[1];
    const float* Whh1 = (const float*)d_in[2];
    const float* bih1 = (const float*)d_in[3];
    const float* bhh1 = (const float*)d_in[4];
    const float* Wih2 = (const float*)d_in[5];
    const float* Whh2 = (const float*)d_in[6];
    const float* bih2 = (const float*)d_in[7];
    const float* bhh2 = (const float*)d_in[8];
    const float* Wl   = (const float*)d_in[9];
    const float* bl   = (const float*)d_in[10];
    float* out = (float*)d_out;

    static constexpr size_t SMEM = 151552;
    hipFuncSetAttribute(reinterpret_cast<const void*>(&lstm2_spec),
                        hipFuncAttributeMaxDynamicSharedMemorySize, (int)SMEM);

    lstm2_spec<<<dim3(256), dim3(512), SMEM, stream>>>(
        x, Wih1, Whh1, bih1, bhh1, Wih2, Whh2, bih2, bhh2, Wl, bl, out);
}